// Round 1
// baseline (383.642 us; speedup 1.0000x reference)
//
#include <hip/hip_runtime.h>
#include <hip/hip_bf16.h>
#include <stdint.h>

#define HIDDEN 256
#define NMEM   1024
#define LOG2E  1.44269504088896340736f

typedef __attribute__((ext_vector_type(8))) short bf16x8;
typedef __attribute__((ext_vector_type(4))) float f32x4;
typedef unsigned short ushort_t;
typedef unsigned int   uint_t;

__device__ __forceinline__ ushort_t f2bf(float f) {
  uint_t u = __builtin_bit_cast(uint_t, f);
  u += 0x7FFFu + ((u >> 16) & 1u);   // round-to-nearest-even (no NaN inputs here)
  return (ushort_t)(u >> 16);
}

__device__ __forceinline__ void gload_lds16(const void* g, void* l) {
  __builtin_amdgcn_global_load_lds(
      (const __attribute__((address_space(1))) uint_t*)g,
      (__attribute__((address_space(3))) uint_t*)l, 16, 0, 0);
}

// ---------------- prep: normalize memories, emit swizzled bf16 m_hat and V^T ----
// ws layout (ushort units):
//   wsm: 32 tiles x 8192  : m_hat tile  [32 m][256 k], 16B-chunk c stored at c^(ml&7)
//   wsv: 32 tiles x 8192  : V^T   tile  [256 d][32 m], 16B-chunk c stored at c^((d>>1)&3)
__global__ void prep_kernel(const float* __restrict__ mem,
                            ushort_t* __restrict__ wsm,
                            ushort_t* __restrict__ wsv) {
  const int m = blockIdx.x;
  const int k = threadIdx.x;
  float v = mem[m * HIDDEN + k];
  float ss = v * v;
  #pragma unroll
  for (int off = 1; off < 64; off <<= 1) ss += __shfl_xor(ss, off);
  __shared__ float red[4];
  if ((k & 63) == 0) red[k >> 6] = ss;
  __syncthreads();
  const float tot = red[0] + red[1] + red[2] + red[3];
  const float inv = 1.0f / fmaxf(sqrtf(tot), 1e-12f);
  const ushort_t hn = f2bf(v * inv);
  const ushort_t hv = f2bf(v);
  const int t = m >> 5, ml = m & 31;
  const int c = k >> 3;                       // k-chunk within row (0..31)
  wsm[t * 8192 + ((ml * 32 + (c ^ (ml & 7))) << 3) + (k & 7)] = hn;
  const int c2 = ml >> 3;                     // m-chunk within V^T row (0..3)
  wsv[t * 8192 + ((k * 4 + (c2 ^ ((k >> 1) & 3))) << 3) + (ml & 7)] = hv;
}

// ---------------- main: fused cosine-softmax memory read -----------------------
// block = 256 threads = 4 waves; wave owns 16 x-rows; 32 KV tiles of 32 memories.
// LDS: [2 bufs x (16KB m_hat + 16KB V^T)] + 4 x 1280B P-tiles = 70656 B
__global__ __launch_bounds__(256, 2) void mem_kernel(
    const float* __restrict__ x, const ushort_t* __restrict__ wsm,
    const ushort_t* __restrict__ wsv, float* __restrict__ out) {
  __shared__ __align__(16) char lds[70656];
  const int tid  = threadIdx.x;
  const int lane = tid & 63;
  const int wave = tid >> 6;
  const int g    = lane >> 4;      // 0..3
  const int lr   = lane & 15;      // 0..15
  const int row0 = blockIdx.x * 64 + wave * 16;

  // ---- load x rows, compute norm, build bf16 A-frags (lane: row lr, k=8g+j mod 32)
  float xf[64];
  const float* xrow = x + (size_t)(row0 + lr) * HIDDEN + g * 8;
  #pragma unroll
  for (int kt = 0; kt < 8; ++kt) {
    float4 a = *(const float4*)(xrow + kt * 32);
    float4 b = *(const float4*)(xrow + kt * 32 + 4);
    xf[kt*8+0]=a.x; xf[kt*8+1]=a.y; xf[kt*8+2]=a.z; xf[kt*8+3]=a.w;
    xf[kt*8+4]=b.x; xf[kt*8+5]=b.y; xf[kt*8+6]=b.z; xf[kt*8+7]=b.w;
  }
  float ss = 0.f;
  #pragma unroll
  for (int i = 0; i < 64; ++i) ss += xf[i] * xf[i];
  ss += __shfl_xor(ss, 16);
  ss += __shfl_xor(ss, 32);
  // fold temperature (x2) and log2(e) into x_hat so p = exp2(s)
  const float scale = (2.0f * LOG2E) / fmaxf(sqrtf(ss), 1e-12f);
  bf16x8 ax[8];
  #pragma unroll
  for (int kt = 0; kt < 8; ++kt) {
    #pragma unroll
    for (int j = 0; j < 8; ++j) ax[kt][j] = (short)f2bf(xf[kt*8+j] * scale);
  }

  const char* gm = (const char*)wsm;
  const char* gv = (const char*)wsv;
  auto stage = [&](int t, int buf) {   // 32KB tile-pair -> LDS, linear, async
    const int base = buf * 32768;
    #pragma unroll
    for (int i = 0; i < 4; ++i) {
      const int off = wave * 4096 + i * 1024;
      gload_lds16(gm + t * 16384 + off + lane * 16, lds + base + off);
      gload_lds16(gv + t * 16384 + off + lane * 16, lds + base + 16384 + off);
    }
  };

  f32x4 o[16];
  const f32x4 z4 = {0.f, 0.f, 0.f, 0.f};
  #pragma unroll
  for (int i = 0; i < 16; ++i) o[i] = z4;
  float den[4] = {0.f, 0.f, 0.f, 0.f};

  const int xr = lr & 7;                         // row-swizzle key (ml&7)
  const int hk = (xr >> 2) & 1;                  // affects kt bit of chunk index
  const int gx = (g ^ (xr & 3)) << 4;            // low chunk bits, byte offset
  const int g2 = (g ^ ((lr >> 1) & 3)) << 4;     // V^T swizzle, byte offset
  const uint_t pbase = 65536u + (uint_t)wave * 1280u;

  stage(0, 0);
  __syncthreads();

  for (int t = 0; t < 32; ++t) {
    const int buf = t & 1;
    if (t < 31) stage(t + 1, buf ^ 1);
    const int mbase = buf * 32768;
    const int vbase = mbase + 16384;

    // ---- S = x_hat . m_hat^T (two 16-col halves), p = exp2(S)
    float pf[8];
    #pragma unroll
    for (int half = 0; half < 2; ++half) {
      const int ml = half * 16 + lr;
      const char* mrb = lds + mbase + ml * 512 + gx;
      f32x4 s = z4;
      #pragma unroll
      for (int kt = 0; kt < 8; ++kt) {
        bf16x8 bfrag = *(const bf16x8*)(mrb + (((kt ^ hk) << 6)));
        s = __builtin_amdgcn_mfma_f32_16x16x32_bf16(ax[kt], bfrag, s, 0, 0, 0);
      }
      #pragma unroll
      for (int r = 0; r < 4; ++r) {
        const float p = exp2f(s[r]);
        den[r] += p;                 // col (half*16+lr) contribution, row 4g+r
        pf[half * 4 + r] = p;
      }
    }

    // ---- P (D-layout) -> LDS [16 n][40 ushort pitch] -> A-frags
    ushort_t* pw = (ushort_t*)(lds + pbase);
    #pragma unroll
    for (int half = 0; half < 2; ++half) {
      #pragma unroll
      for (int r = 0; r < 4; ++r)
        pw[(4 * g + r) * 40 + half * 16 + lr] = f2bf(pf[half * 4 + r]);
    }
    asm volatile("s_waitcnt lgkmcnt(0)" ::: "memory");
    __builtin_amdgcn_sched_barrier(0);
    const bf16x8 pa = *(const bf16x8*)(lds + pbase + lr * 80 + g * 16);

    // ---- O += P @ V  (16 d-fragments of 16 cols)
    const char* vrb = lds + vbase + lr * 64 + g2;
    #pragma unroll
    for (int d0 = 0; d0 < 16; ++d0) {
      bf16x8 vfrag = *(const bf16x8*)(vrb + d0 * 1024);
      o[d0] = __builtin_amdgcn_mfma_f32_16x16x32_bf16(pa, vfrag, o[d0], 0, 0, 0);
    }
    __syncthreads();
  }

  // ---- denominator reduce across the 16 lanes of each row-group
  #pragma unroll
  for (int r = 0; r < 4; ++r) {
    den[r] += __shfl_xor(den[r], 1);
    den[r] += __shfl_xor(den[r], 2);
    den[r] += __shfl_xor(den[r], 4);
    den[r] += __shfl_xor(den[r], 8);
  }

  float* op = out + (size_t)(row0 + 4 * g) * HIDDEN + lr;
  #pragma unroll
  for (int r = 0; r < 4; ++r) {
    const float rd = 1.0f / den[r];
    #pragma unroll
    for (int d0 = 0; d0 < 16; ++d0)
      op[r * HIDDEN + d0 * 16] = o[d0][r] * rd;
  }
}

extern "C" void kernel_launch(void* const* d_in, const int* in_sizes, int n_in,
                              void* d_out, int out_size, void* d_ws, size_t ws_size,
                              hipStream_t stream) {
  const float* x   = (const float*)d_in[0];
  const float* mem = (const float*)d_in[1];
  float* out = (float*)d_out;
  const int N = in_sizes[0] / HIDDEN;          // 131072

  ushort_t* wsm = (ushort_t*)d_ws;             // 512 KB
  ushort_t* wsv = wsm + NMEM * HIDDEN;         // 512 KB

  prep_kernel<<<NMEM, HIDDEN, 0, stream>>>(mem, wsm, wsv);
  mem_kernel<<<N / 64, 256, 0, stream>>>(x, wsm, wsv, out);
}